// Round 2
// baseline (6530.733 us; speedup 1.0000x reference)
//
#include <hip/hip_runtime.h>
#include <stdint.h>

// LoraLSTM on MI355X. FP32 I/O, bf16 internal pipeline.
//  R8 changes vs R7:
//   - XCD-colocated recurrence: 256 WGs launched; election via per-XCD rank
//     counters (s_getreg XCC_ID) picks two groups of 16 WGs, each group
//     provably on ONE XCD. h exchange uses sc0 (L1-bypass, L2-coherent
//     within the XCD) -> ~200cy RT instead of ~700cy MALL RT.
//     Safety: writers mirror packets to a shadow buffer with sc1 (MALL);
//     readers fall back (sticky) to shadow after 16 failed sc0 rounds.
//   - reader-major hbuf layout: per-thread 256B contiguous -> one asm block
//     of 16 global_load_dwordx4 (imm offsets) + single vmcnt(0); retry
//     re-issues the whole block (zero per-round address VALU).
//   - gx stored by GEMM in MFMA-fragment order (bias folded, bf16 r-quads):
//     rec prefetch = 4 x b64 loads + unpack, no scalar gx loads.
//   - 2 barriers/step.

typedef unsigned short u16;
typedef unsigned long long u64;
typedef __bf16 bf16x8 __attribute__((ext_vector_type(8)));
typedef float f32x4 __attribute__((ext_vector_type(4)));
typedef int i32x4 __attribute__((ext_vector_type(4)));

#define NCELL 4
#define HID 512
#define INP 1024
#define G4 2048
#define BATCH 32
#define SEQ 512
#define RLORA 8
#define NW 16   // workgroups per direction in recurrence
#define HPW 32  // HID / NW
#define HTAGN 8192  // tagged u64 packets per dir per parity (2 h each)

__device__ __forceinline__ float bf2f(u16 u) {
  union { uint32_t i; float f; } v;
  v.i = ((uint32_t)u) << 16;
  return v.f;
}
__device__ __forceinline__ u16 f2bf(float f) {
  union { float f; uint32_t i; } v;
  v.f = f;
  uint32_t lsb = (v.i >> 16) & 1;
  return (u16)((v.i + 0x7fffu + lsb) >> 16);
}
__device__ __forceinline__ float asf(uint32_t u) {
  union { uint32_t i; float f; } v;
  v.i = u;
  return v.f;
}
__device__ __forceinline__ float sigm(float x) {
  return __builtin_amdgcn_rcpf(1.f + __expf(-x));
}
__device__ __forceinline__ float ftanh(float x) {
  return 1.f - 2.f * __builtin_amdgcn_rcpf(__expf(2.f * x) + 1.f);
}

// 16 x dwordx4 batched poll loads, single vmcnt. CB = cache bits string.
#define POLL16(Q, BASE, CB)                                            \
  asm volatile(                                                        \
      "global_load_dwordx4 %[q0], %[b], off " CB "\n\t"                \
      "global_load_dwordx4 %[q1], %[b], off offset:16 " CB "\n\t"      \
      "global_load_dwordx4 %[q2], %[b], off offset:32 " CB "\n\t"      \
      "global_load_dwordx4 %[q3], %[b], off offset:48 " CB "\n\t"      \
      "global_load_dwordx4 %[q4], %[b], off offset:64 " CB "\n\t"      \
      "global_load_dwordx4 %[q5], %[b], off offset:80 " CB "\n\t"      \
      "global_load_dwordx4 %[q6], %[b], off offset:96 " CB "\n\t"      \
      "global_load_dwordx4 %[q7], %[b], off offset:112 " CB "\n\t"     \
      "global_load_dwordx4 %[q8], %[b], off offset:128 " CB "\n\t"     \
      "global_load_dwordx4 %[q9], %[b], off offset:144 " CB "\n\t"     \
      "global_load_dwordx4 %[q10], %[b], off offset:160 " CB "\n\t"    \
      "global_load_dwordx4 %[q11], %[b], off offset:176 " CB "\n\t"    \
      "global_load_dwordx4 %[q12], %[b], off offset:192 " CB "\n\t"    \
      "global_load_dwordx4 %[q13], %[b], off offset:208 " CB "\n\t"    \
      "global_load_dwordx4 %[q14], %[b], off offset:224 " CB "\n\t"    \
      "global_load_dwordx4 %[q15], %[b], off offset:240 " CB "\n\t"    \
      "s_waitcnt vmcnt(0)"                                             \
      : [q0] "=v"(Q[0]), [q1] "=v"(Q[1]), [q2] "=v"(Q[2]),             \
        [q3] "=v"(Q[3]), [q4] "=v"(Q[4]), [q5] "=v"(Q[5]),             \
        [q6] "=v"(Q[6]), [q7] "=v"(Q[7]), [q8] "=v"(Q[8]),             \
        [q9] "=v"(Q[9]), [q10] "=v"(Q[10]), [q11] "=v"(Q[11]),         \
        [q12] "=v"(Q[12]), [q13] "=v"(Q[13]), [q14] "=v"(Q[14]),       \
        [q15] "=v"(Q[15])                                              \
      : [b] "v"(BASE)                                                  \
      : "memory")

// ---------------- weight folding: W_eff = W + 2 * BL @ A  (fp32 in, bf16 out) ---------
template <int K>
__global__ void fold_kernel(const float* __restrict__ w, const float* __restrict__ a,
                            const float* __restrict__ bl, u16* __restrict__ weff) {
  int64_t idx = (int64_t)blockIdx.x * blockDim.x + threadIdx.x;
  if (idx >= (int64_t)NCELL * G4 * K) return;
  int d = (int)(idx % K);
  int64_t gc = idx / K;
  int cell = (int)(gc / G4);
  float acc = w[idx];
#pragma unroll
  for (int r = 0; r < RLORA; ++r)
    acc += 2.0f * bl[gc * RLORA + r] * a[(int64_t)cell * RLORA * K + r * K + d];
  weff[idx] = f2bf(acc);
}

__global__ void bias_kernel(const float* __restrict__ b_ih, const float* __restrict__ b_hh,
                            float* __restrict__ bias) {
  int i = blockIdx.x * blockDim.x + threadIdx.x;
  if (i < NCELL * G4) bias[i] = b_ih[i] + b_hh[i];
}

// ---------------- gx chunk GEMM (writes fragment-order bf16 gx, bias folded) ----------
template <bool AF32>
__global__ __launch_bounds__(256) void gemm_kernel(const void* __restrict__ Ain,
                                                   const u16* __restrict__ W,
                                                   const float* __restrict__ bias,
                                                   u16* __restrict__ gx,
                                                   uint32_t* __restrict__ elect, int tw0,
                                                   int tw1, int CL, int clsh) {
  __shared__ alignas(16) u16 As[128][72];
  __shared__ alignas(16) u16 Bs[128][72];
  const int tid = threadIdx.x;
  // zero the election block for the rec launch that follows this dispatch
  if (blockIdx.x == 0 && blockIdx.y == 0 && blockIdx.z == 0 && tid < 16) elect[tid] = 0;
  const int dir = blockIdx.z;
  const int m0 = blockIdx.x * 128;
  const int n0 = blockIdx.y * 128;
  const int tw = dir ? tw1 : tw0;
  const u16* Wc = W + (int64_t)dir * G4 * INP;
  const float* bc = bias + dir * G4;
  u16* gxc = gx + (size_t)dir * CL * 65536;  // 65536 u16 per lcol
  const int wave = tid >> 6, lane = tid & 63;
  const int wm = wave & 1, wn = wave >> 1;
  const int llo = lane & 15, lhi = lane >> 4;

  // M-row remap: tile row rho -> (b, lcol) with b = bb + (rho&3), lcol = (rho>>2)&(CL-1)
  int64_t aoff[4];
  const u16* bptr[4];
  int srow[4], ssc[4];
#pragma unroll
  for (int i = 0; i < 4; ++i) {
    int s = i * 256 + tid;
    srow[i] = s >> 3;
    ssc[i] = s & 7;
    int rho = m0 + srow[i];
    int b = ((rho >> (clsh + 2)) << 2) | (rho & 3);
    int lcol = (rho >> 2) & (CL - 1);
    int tt = tw + lcol;
    aoff[i] = ((int64_t)b * SEQ + tt) * INP + ssc[i] * 8;
    bptr[i] = Wc + (int64_t)(n0 + srow[i]) * INP + ssc[i] * 8;
  }

  const f32x4 fzero = {0.f, 0.f, 0.f, 0.f};
  f32x4 acc[4][4];
#pragma unroll
  for (int i = 0; i < 4; ++i)
#pragma unroll
    for (int j = 0; j < 4; ++j) acc[i][j] = fzero;

  for (int kt = 0; kt < INP / 64; ++kt) {
    const int kb = kt * 64;
    __syncthreads();
#pragma unroll
    for (int i = 0; i < 4; ++i) {
      if (AF32) {
        const float* src = (const float*)Ain + aoff[i] + kb;
        uint32_t p[4];
#pragma unroll
        for (int q = 0; q < 4; ++q)
          p[q] = (uint32_t)f2bf(src[2 * q]) | ((uint32_t)f2bf(src[2 * q + 1]) << 16);
        *(uint4*)&As[srow[i]][ssc[i] * 8] = make_uint4(p[0], p[1], p[2], p[3]);
      } else {
        *(uint4*)&As[srow[i]][ssc[i] * 8] = *(const uint4*)((const u16*)Ain + aoff[i] + kb);
      }
      *(uint4*)&Bs[srow[i]][ssc[i] * 8] = *(const uint4*)(bptr[i] + kb);
    }
    __syncthreads();
#pragma unroll
    for (int ks = 0; ks < 2; ++ks) {
      bf16x8 af[4], bfr[4];
#pragma unroll
      for (int i = 0; i < 4; ++i) {
        af[i] = *(const bf16x8*)&As[wm * 64 + i * 16 + llo][ks * 32 + lhi * 8];
        bfr[i] = *(const bf16x8*)&Bs[wn * 64 + i * 16 + llo][ks * 32 + lhi * 8];
      }
#pragma unroll
      for (int i = 0; i < 4; ++i)
#pragma unroll
        for (int j = 0; j < 4; ++j)
          acc[i][j] = __builtin_amdgcn_mfma_f32_16x16x32_bf16(af[i], bfr[j], acc[i][j], 0, 0, 0);
    }
  }
  // epilogue: fragment-order bf16 store (r-quad per b64), bias folded
  const int bb = ((m0 >> (clsh + 2)) << 2);
  const int mt_ = bb >> 4;
  const int lhiR = (bb >> 2) & 3;
  const int lc0 = (m0 >> 2) & (CL - 1);
#pragma unroll
  for (int jg = 0; jg < 4; ++jg) {
    const int cb0 = n0 + wn * 64 + jg * 16;
    const int wgp = (cb0 >> 5) & 15;
    const int jp = (cb0 >> 4) & 1;
    const int wvp = cb0 >> 9;
    const float bv = bc[cb0 + llo];
    const size_t cbase =
        (size_t)wgp * 4096 + (size_t)wvp * 1024 + mt_ * 512 + jp * 256 + (lhiR * 16 + llo) * 4;
#pragma unroll
    for (int i = 0; i < 4; ++i) {
      const int lcol = lc0 + wm * 16 + i * 4 + lhi;
      u64 v = (u64)f2bf(acc[i][jg][0] + bv) | ((u64)f2bf(acc[i][jg][1] + bv) << 16) |
              ((u64)f2bf(acc[i][jg][2] + bv) << 32) | ((u64)f2bf(acc[i][jg][3] + bv) << 48);
      *(u64*)(gxc + (size_t)lcol * 65536 + cbase) = v;
    }
  }
}

// ---------------- recurrence chunk ----------------
template <bool OUTF32>
__global__ __launch_bounds__(256, 1) void rec_kernel(
    const u16* __restrict__ gx,    // [2][CL][frag 65536 u16] bf16, bias folded
    const u16* __restrict__ Whh,   // [2][G4][HID] bf16
    u64* __restrict__ hbuf,        // [2 dirs][2 par][HTAGN] primary (sc0/L2)
    u64* __restrict__ hsh,         // shadow (sc1/MALL)
    uint32_t* __restrict__ elect,  // [16]: cnt[8], claim, map[2]
    void* __restrict__ outp,
    float* __restrict__ hn, float* __restrict__ cn,
    float* __restrict__ cstate,    // [4 cells][B][H] fp32 (ws)
    int cell_base, int s0, int CL) {
  const int tid = threadIdx.x;
  __shared__ alignas(16) u16 h_lds[2 * 16 * 64 * 8];  // fragment order, 32KB
  __shared__ alignas(16) float g_lds[4][BATCH][HPW + 4];
  __shared__ uint32_t e_sh[2];

  // ---- election: groups of 16 WGs colocated on one XCD claim dir 0/1 ----
  if (tid == 0) {
    uint32_t xcc;
    asm volatile("s_getreg_b32 %0, hwreg(20, 0, 32)" : "=s"(xcc));
    uint32_t xcd = xcc & 7;
    uint32_t rank = atomicAdd(&elect[xcd], 1u);
    uint32_t grp = rank >> 4, grank = rank & 15;
    uint32_t key = (xcd << 16) | (grp + 1);
    if (grank == 15) {
      uint32_t pos = atomicAdd(&elect[8], 1u);
      if (pos < 2)
        __hip_atomic_store(&elect[9 + pos], key, __ATOMIC_RELAXED, __HIP_MEMORY_SCOPE_AGENT);
    }
    uint32_t dirw;
    for (;;) {
      uint32_t m0 = __hip_atomic_load(&elect[9], __ATOMIC_RELAXED, __HIP_MEMORY_SCOPE_AGENT);
      uint32_t m1 = __hip_atomic_load(&elect[10], __ATOMIC_RELAXED, __HIP_MEMORY_SCOPE_AGENT);
      if (m0 == key) { dirw = 1; break; }
      if (m1 == key) { dirw = 2; break; }
      if (m0 && m1) { dirw = 0; break; }
    }
    e_sh[0] = dirw;
    e_sh[1] = grank;
  }
  __syncthreads();
  if (e_sh[0] == 0) return;
  const int dir = (int)e_sh[0] - 1;
  const int wg = (int)e_sh[1];
  const int hb = wg * HPW;
  const int wave = tid >> 6, lane = tid & 63;
  const int llo = lane & 15, lhi = lane >> 4;

  const u16* gxc = gx + (size_t)dir * CL * 65536;
  const u16* Wc = Whh + (int64_t)dir * G4 * HID;
  u64* ht_dir = hbuf + (size_t)dir * (2 * HTAGN);
  u64* hs_dir = hsh + (size_t)dir * (2 * HTAGN);
  float* cst = cstate + (int64_t)(cell_base + dir) * BATCH * HID;

  // W_hh fragments for this wave's gate, held for the whole chunk.
  uint4 wfrag[2][16];
#pragma unroll
  for (int j = 0; j < 2; ++j)
#pragma unroll
    for (int ks = 0; ks < 16; ++ks) {
      const int col = wave * HID + hb + j * 16 + llo;
      wfrag[j][ks] = *(const uint4*)(Wc + (int64_t)col * HID + ks * 32 + lhi * 8);
    }
  if (s0 == 0) {
    for (int i = tid; i < 2 * 16 * 64 * 8 / 2; i += 256) ((uint32_t*)h_lds)[i] = 0;
  }
  // c state in registers (thread-private: this thread owns (b=cb, hb+j0..j0+3))
  const int cb = tid >> 3, j0 = (tid & 7) * 4;
  float creg[4];
#pragma unroll
  for (int u = 0; u < 4; ++u) creg[u] = (s0 == 0) ? 0.f : cst[cb * HID + hb + j0 + u];
  // writer's packet address: pure frag u64 index F -> reader-major byte layout
  const int wmt = cb >> 4;
  const int Fw = ((wmt * 16 + wg) * 64 + (j0 >> 3) * 16 + (cb & 15)) * 2 + ((j0 >> 2) & 1);
  const int widx = (Fw & 255) * 32 + (Fw >> 8) * 2;  // u64 units
  int sticky = 0;

  for (int s = s0; s < s0 + CL; ++s) {
    const int ls = s - s0;
    const int t = dir ? (SEQ - 1 - s) : s;
    const int lcol = dir ? (CL - 1 - ls) : ls;
    // gx prefetch: 4 x b64 fragment loads (complete during the poll's vmcnt)
    const u64* gp = (const u64*)gxc + (size_t)lcol * 16384 + wg * 1024 + wave * 256 + lane;
    u64 g4[4];
    g4[0] = gp[0];
    g4[1] = gp[64];
    g4[2] = gp[128];
    g4[3] = gp[192];
    if (s > 0) {
      const uint32_t want = (uint32_t)s;
      const int par = (s - 1) & 1;
      const u64 pb = (u64)(ht_dir + (size_t)par * HTAGN + tid * 32);
      const u64 pbs = (u64)(hs_dir + (size_t)par * HTAGN + tid * 32);
      i32x4 q[16];
      int rounds = 0;
      for (;;) {
        if (sticky == 0) {
          POLL16(q, pb, "sc0");
        } else {
          POLL16(q, pbs, "sc0 sc1");
        }
        uint32_t bad = 0;
#pragma unroll
        for (int k = 0; k < 16; ++k)
          bad |= ((uint32_t)q[k][1] ^ want) | ((uint32_t)q[k][3] ^ want);
        if (bad == 0) break;
        if (++rounds >= 16) sticky = 1;
      }
      // stage payloads into fragment-order LDS (conflict-free 8B/lane)
      uint32_t* hd = (uint32_t*)h_lds;
#pragma unroll
      for (int k = 0; k < 16; ++k) {
        hd[2 * tid + k * 512] = (uint32_t)q[k][0];
        hd[2 * tid + k * 512 + 1] = (uint32_t)q[k][2];
      }
    }
    __syncthreads();  // staged h (or zeros at s==0) visible; also protects g_lds reuse
    // unpack gx fragments -> acc
    f32x4 acc[2][2];
#pragma unroll
    for (int mt = 0; mt < 2; ++mt)
#pragma unroll
      for (int j = 0; j < 2; ++j) {
        const u64 g = g4[mt * 2 + j];
        const uint32_t lo = (uint32_t)g, hi = (uint32_t)(g >> 32);
        acc[mt][j][0] = asf(lo << 16);
        acc[mt][j][1] = asf(lo & 0xffff0000u);
        acc[mt][j][2] = asf(hi << 16);
        acc[mt][j][3] = asf(hi & 0xffff0000u);
      }
#pragma unroll
    for (int ks = 0; ks < 16; ++ks) {
      bf16x8 af[2];
#pragma unroll
      for (int mt = 0; mt < 2; ++mt)
        af[mt] = *(const bf16x8*)&h_lds[((mt * 16 + ks) * 64 + lane) * 8];
#pragma unroll
      for (int mt = 0; mt < 2; ++mt)
#pragma unroll
        for (int j = 0; j < 2; ++j)
          acc[mt][j] = __builtin_amdgcn_mfma_f32_16x16x32_bf16(
              af[mt], __builtin_bit_cast(bf16x8, wfrag[j][ks]), acc[mt][j], 0, 0, 0);
    }
    // cross-wave gate exchange
#pragma unroll
    for (int mt = 0; mt < 2; ++mt)
#pragma unroll
      for (int j = 0; j < 2; ++j)
#pragma unroll
        for (int r = 0; r < 4; ++r)
          g_lds[wave][mt * 16 + lhi * 4 + r][j * 16 + llo] = acc[mt][j][r];
    __syncthreads();
    float hv[4], cv[4];
    u16 h16[4];
    {
      const f32x4 gi = *(const f32x4*)&g_lds[0][cb][j0];
      const f32x4 gf = *(const f32x4*)&g_lds[1][cb][j0];
      const f32x4 gg = *(const f32x4*)&g_lds[2][cb][j0];
      const f32x4 go = *(const f32x4*)&g_lds[3][cb][j0];
#pragma unroll
      for (int u = 0; u < 4; ++u) {
        float c = creg[u];
        c = sigm(gf[u]) * c + sigm(gi[u]) * ftanh(gg[u]);
        hv[u] = sigm(go[u]) * ftanh(c);
        cv[u] = c;
        creg[u] = c;
        h16[u] = f2bf(hv[u]);
      }
    }
    {  // tagged packets: primary sc0 (L2) + shadow sc1 (MALL)
      const u64 tg = ((u64)(uint32_t)(s + 1)) << 32;
      const u64 p0 = tg | (u64)((uint32_t)h16[0] | ((uint32_t)h16[1] << 16));
      const u64 p1 = tg | (u64)((uint32_t)h16[2] | ((uint32_t)h16[3] << 16));
      const u64 wa = (u64)(ht_dir + (size_t)(s & 1) * HTAGN + widx);
      const u64 was = (u64)(hs_dir + (size_t)(s & 1) * HTAGN + widx);
      asm volatile(
          "global_store_dwordx2 %[a], %[p0], off sc0\n\t"
          "global_store_dwordx2 %[a], %[p1], off offset:8 sc0\n\t"
          "global_store_dwordx2 %[as], %[p0], off sc1\n\t"
          "global_store_dwordx2 %[as], %[p1], off offset:8 sc1"
          :: [a] "v"(wa), [as] "v"(was), [p0] "v"(p0), [p1] "v"(p1)
          : "memory");
    }
    // non-critical stores off the exchange path
    {
      const int64_t obase = ((int64_t)cb * SEQ + t) * (2 * HID) + dir * HID + hb + j0;
      if (OUTF32) {
        *(float4*)((float*)outp + obase) = make_float4(hv[0], hv[1], hv[2], hv[3]);
      } else {
        uint32_t* ow = (uint32_t*)((u16*)outp + obase);
        ow[0] = (uint32_t)h16[0] | ((uint32_t)h16[1] << 16);
        ow[1] = (uint32_t)h16[2] | ((uint32_t)h16[3] << 16);
      }
      if (s == SEQ - 1) {
        const int cg = cell_base + dir;
        const int64_t nbase = ((int64_t)cg * BATCH + cb) * HID + hb + j0;
        *(float4*)(hn + nbase) = make_float4(hv[0], hv[1], hv[2], hv[3]);
        *(float4*)(cn + nbase) = make_float4(cv[0], cv[1], cv[2], cv[3]);
      }
    }
  }
  // persist c for next chunk
#pragma unroll
  for (int u = 0; u < 4; ++u) cst[cb * HID + hb + j0 + u] = creg[u];
}

extern "C" void kernel_launch(void* const* d_in, const int* in_sizes, int n_in, void* d_out,
                              int out_size, void* d_ws, size_t ws_size, hipStream_t stream) {
  const float* x = (const float*)d_in[0];
  const float* w_ih = (const float*)d_in[1];
  const float* w_hh = (const float*)d_in[2];
  const float* b_ih = (const float*)d_in[3];
  const float* b_hh = (const float*)d_in[4];
  const float* a_ih = (const float*)d_in[5];
  const float* bl_ih = (const float*)d_in[6];
  const float* a_hh = (const float*)d_in[7];
  const float* bl_hh = (const float*)d_in[8];
  float* out = (float*)d_out;  // fp32 outputs

  char* ws = (char*)d_ws;
  const size_t O_WIH = 0;                                          // 16,777,216
  const size_t O_WHH = O_WIH + (size_t)NCELL * G4 * INP * 2;       // + 8,388,608
  const size_t O_BIAS = O_WHH + (size_t)NCELL * G4 * HID * 2;      // + 32,768
  const size_t O_CST = O_BIAS + (size_t)NCELL * G4 * 4;            // + 262,144
  const size_t O_HBUF = O_CST + (size_t)NCELL * BATCH * HID * 4;   // + 524,288 (primary)
  const size_t O_HSH = O_HBUF + (size_t)2 * 2 * 2 * HTAGN * 8;     // + 524,288 (shadow)
  const size_t O_ELECT = O_HSH + (size_t)2 * 2 * 2 * HTAGN * 8;    // + 256
  const size_t O_MID = O_ELECT + 256;                              // + 33,554,432
  const size_t O_GX = O_MID + (size_t)BATCH * SEQ * 2 * HID * 2;   // + gx (bf16 frag)
  u16* w_ih_eff = (u16*)(ws + O_WIH);
  u16* w_hh_eff = (u16*)(ws + O_WHH);
  float* bias = (float*)(ws + O_BIAS);
  float* cstate = (float*)(ws + O_CST);
  u64* hbuf = (u64*)(ws + O_HBUF);
  u64* hshadow = (u64*)(ws + O_HSH);
  uint32_t* elect = (uint32_t*)(ws + O_ELECT);
  u16* mid = (u16*)(ws + O_MID);
  u16* gxb = (u16*)(ws + O_GX);

  int CL = 128;
  while (CL > 32 && O_GX + (size_t)2 * BATCH * CL * G4 * 2 > ws_size) CL >>= 1;
  const int nch = SEQ / CL;
  int clsh = 31 - __builtin_clz((unsigned)CL);

  // zero all step tags once per run (primary + shadow)
  (void)hipMemsetAsync(ws + O_HBUF, 0, (size_t)2 * 2 * 2 * 2 * HTAGN * 8, stream);

  {
    int64_t tot = (int64_t)NCELL * G4 * INP;
    fold_kernel<INP><<<(int)((tot + 255) / 256), 256, 0, stream>>>(w_ih, a_ih, bl_ih, w_ih_eff);
  }
  {
    int64_t tot = (int64_t)NCELL * G4 * HID;
    fold_kernel<HID><<<(int)((tot + 255) / 256), 256, 0, stream>>>(w_hh, a_hh, bl_hh, w_hh_eff);
  }
  bias_kernel<<<(NCELL * G4 + 255) / 256, 256, 0, stream>>>(b_ih, b_hh, bias);

  float* hn = out + (size_t)BATCH * SEQ * (2 * HID);
  float* cn = hn + (size_t)NCELL * BATCH * HID;

  dim3 gemm_grid(BATCH * CL / 128, G4 / 128, 2);
  for (int layer = 0; layer < 2; ++layer) {
    const u16* wih = w_ih_eff + (size_t)layer * 2 * G4 * INP;
    const u16* whh = w_hh_eff + (size_t)layer * 2 * G4 * HID;
    const float* bi = bias + (size_t)layer * 2 * G4;
    u64* hbL = hbuf + (size_t)layer * 4 * HTAGN;
    u64* hsL = hshadow + (size_t)layer * 4 * HTAGN;
    for (int ci = 0; ci < nch; ++ci) {
      const int tw0 = ci * CL;
      const int tw1 = SEQ - (ci + 1) * CL;
      if (layer == 0) {
        gemm_kernel<true><<<gemm_grid, 256, 0, stream>>>(x, wih, bi, gxb, elect, tw0, tw1, CL,
                                                         clsh);
        rec_kernel<false><<<256, 256, 0, stream>>>(gxb, whh, hbL, hsL, elect, mid, hn, cn,
                                                   cstate, 0, ci * CL, CL);
      } else {
        gemm_kernel<false><<<gemm_grid, 256, 0, stream>>>(mid, wih, bi, gxb, elect, tw0, tw1,
                                                          CL, clsh);
        rec_kernel<true><<<256, 256, 0, stream>>>(gxb, whh, hbL, hsL, elect, out, hn, cn,
                                                  cstate, 2, ci * CL, CL);
      }
    }
  }
}